// Round 17
// baseline (89.284 us; speedup 1.0000x reference)
//
#include <hip/hip_runtime.h>
#include <hip/hip_fp16.h>

// ---------------------------------------------------------------------------
// 9-qubit batched state-vector simulator, v21 (resubmit x3 — R14/R15/R16 were
// all GPU-acquisition timeouts; this kernel has never been measured).
// v20 (tan-form gates, qsim ~40µs) confirmed VALU reduction pays; the
// sub-proportional gain (-16% vs -33% VALU removed) says DS latency is now
// co-binding. v21 re-opens the ILP lever at the NEW balance: v18's verified
// 4-element phase-skewed structure (A|B|C|D, LDS_FENCE discipline) + v20's
// verified tan-form gates (T=tan(theta/2), 2 FMA/pair, cosines deferred into
// D-tables at qtab time + one f32 scale at output). Mechanical merge of two
// measured-correct components; all layouts/Sig3/Walsh = v13 verbatim.
// ---------------------------------------------------------------------------

typedef float v2f __attribute__((ext_vector_type(2)));
typedef _Float16 v2h __attribute__((ext_vector_type(2)));

#define LDS_FENCE() asm volatile("" ::: "memory")

constexpr int pf(int l, int i) {        // forward CNOT-ring basis map, layer l
    const int r = l + 1; int j = i;
    for (int c = 0; c < 9; ++c) {
        const int bit = (j >> (8 - c)) & 1;
        const int t = (c + r) % 9;
        j ^= bit << (8 - t);
    }
    return j;
}

struct PMask { int m[2][9]; };
constexpr PMask make_pmask() {
    PMask pm{};
    for (int bd = 0; bd < 2; ++bd)
        for (int q = 0; q < 9; ++q) {
            const int img = pf(bd, 1 << q);
            for (int p = 0; p < 9; ++p)
                if ((img >> p) & 1) pm.m[bd][p] |= 1 << q;
        }
    return pm;
}
constexpr PMask PM = make_pmask();

// ---- sigma3 per boundary: img[b] = dest bit of source bit b; bits 0..2 id ----
struct Sig3 {
    int wbasis[6];   // sigma3(pf(l, 1<<b))        b = lane bit (C layout)
    int koff[8];     // sigma3(pf(l, k<<6))        k = reg index (C layout)
    int rimg[6];     // dest bit of source bit 3+b (for A-read base)
};
constexpr Sig3 make_sig3(int l) {
    Sig3 out{};
    for (int limit = 2; limit <= 64; limit *= 2) {
        for (int idx = 0; idx < 720; ++idx) {
            int pool[6] = {3, 4, 5, 6, 7, 8};
            int perm[6] = {};
            int f = idx;
            const int fact[6] = {120, 24, 6, 2, 1, 1};
            int n = 6;
            for (int pos = 0; pos < 6; ++pos) {
                const int sel = f / fact[pos]; f %= fact[pos];
                perm[pos] = pool[sel];
                for (int m2 = sel; m2 + 1 < n; ++m2) pool[m2] = pool[m2 + 1];
                --n;
            }
            int img[9] = {0, 1, 2, perm[0], perm[1], perm[2],
                          perm[3], perm[4], perm[5]};
            int cnt[32] = {};
            bool ok = true;
            for (int L = 0; L < 64 && ok; ++L) {
                const int j = pf(l, L);
                int addr = 0;
                for (int bb = 0; bb < 9; ++bb)
                    if ((j >> bb) & 1) addr ^= 1 << img[bb];
                if (++cnt[addr & 31] > limit) ok = false;
            }
            if (ok) {
                for (int b2 = 0; b2 < 6; ++b2) {
                    const int j = pf(l, 1 << b2); int v = 0;
                    for (int bb = 0; bb < 9; ++bb)
                        if ((j >> bb) & 1) v ^= 1 << img[bb];
                    out.wbasis[b2] = v;
                }
                for (int k = 0; k < 8; ++k) {
                    const int j = pf(l, k << 6); int v = 0;
                    for (int bb = 0; bb < 9; ++bb)
                        if ((j >> bb) & 1) v ^= 1 << img[bb];
                    out.koff[k] = v;
                }
                for (int b2 = 0; b2 < 6; ++b2) out.rimg[b2] = img[3 + b2];
                return out;
            }
        }
    }
    return out;
}
constexpr Sig3 S3_0 = make_sig3(0);
constexpr Sig3 S3_1 = make_sig3(1);

#define PI_F    3.14159265358979323846f
#define INV2PI  0.15915494309189535f

static __device__ inline unsigned pack_rn(float x, float y) {
    const __half2 h = __floats2half2_rn(x, y);
    return *(const unsigned*)&h;
}

// ws layout (u32/float units):
//   [0..27)       gates: 27 u32 = half2{T,T}, T = tan(theta/2)
//   [27]          f32 final scale = (prod_w cos(theta_l2_w/2))^2
//   [64..576)     D0h: 512 u32 = half2{dx,dy} * prodc(L0)  boundary 1->2
//   [576..1088)   D1h: 512 u32 = half2 * prodc(L1)         boundary 2->3
//   [1088..2112)  PH : 512 v2f (fp32) init-state phase
__global__ __launch_bounds__(512) void qtab_kernel(
        const float* __restrict__ wt, float* __restrict__ ws) {
    const int j = threadIdx.x;             // 0..511
    unsigned* wu = (unsigned*)ws;
    if (j < 27) {
        float s, c; __sincosf(0.5f * wt[j * 3 + 1], &s, &c);
        const float t = s / c;
        wu[j] = pack_rn(t, t);
    }
    // per-layer cosine products (wave-uniform; cheap, computed by all)
    float C[3];
    #pragma unroll
    for (int l = 0; l < 3; ++l) {
        float p = 1.0f;
        #pragma unroll
        for (int w = 0; w < 9; ++w) {
            float s, c; __sincosf(0.5f * wt[(l * 9 + w) * 3 + 1], &s, &c);
            p *= c;
        }
        C[l] = p;
    }
    if (j == 0) ws[27] = C[2] * C[2];
    #pragma unroll
    for (int bd = 0; bd < 2; ++bd) {
        float alpha = 0.0f;
        #pragma unroll
        for (int p = 0; p < 9; ++p) {
            const int w = 8 - p;
            const float om = wt[(bd * 9 + w) * 3 + 2];        // omega, layer bd
            const float ph = wt[((bd + 1) * 9 + w) * 3 + 0];  // phi, layer bd+1
            alpha += ((j >> p) & 1) ? 0.5f * om : -0.5f * om;
            alpha += (__popc(j & PM.m[bd][p]) & 1) ? 0.5f * ph : -0.5f * ph;
        }
        float sn, cs; __sincosf(alpha, &sn, &cs);
        wu[64 + bd * 512 + j] = pack_rn(cs * C[bd], sn * C[bd]);
    }
    {
        float a = 0.0f;
        #pragma unroll
        for (int p = 0; p < 9; ++p) {
            const int w = 8 - p;
            const float phi = wt[w * 3 + 0];
            a += ((j >> p) & 1) ? (0.5f * phi - 0.5f * PI_F) : (-0.5f * phi);
        }
        float sn, cs; __sincosf(a, &sn, &cs);
        ((v2f*)(ws + 1088))[j] = (v2f){cs, sn};
    }
}

// tan-form packed-fp16 real-Y gate, in-place, T from ONE SGPR = half2{t,t}:
//   a0' = a0 - T*a1 ; a1' = a1 + T*a0   (uniform cos factor deferred)
#define APPLY_GATE(ar, T, KB)                                                 \
    {                                                                         \
        _Pragma("unroll")                                                     \
        for (int k0 = 0; k0 < 8; ++k0) if (!(k0 & (KB))) {                    \
            const int k1 = k0 | (KB);                                         \
            unsigned t;                                                       \
            asm("v_pk_fma_f16 %0, %1, %2, %3 neg_lo:[1,0,0] neg_hi:[1,0,0]"   \
                : "=v"(t) : "s"(T), "v"(ar[k1]), "v"(ar[k0]));                \
            asm("v_pk_fma_f16 %0, %1, %2, %0"                                 \
                : "+v"(ar[k1]) : "s"(T), "v"(ar[k0]));                        \
            ar[k0] = t;                                                       \
        }                                                                     \
    }

// LDS round-trip transpose with compiler fences (cross-lane handoff is
// invisible to per-thread alias analysis — v16/v17 lesson)
#define XPOSE(ar, wb, rb)                                                     \
    {                                                                         \
        LDS_FENCE();                                                          \
        _Pragma("unroll")                                                     \
        for (int k = 0; k < 8; ++k) S[(wb) + (k << 5)] = ar[k];               \
        LDS_FENCE();                                                          \
        const uint4 r0 = S4[((rb) >> 2)];                                     \
        const uint4 r1 = S4[((rb) >> 2) + 1];                                 \
        ar[0] = r0.x; ar[1] = r0.y; ar[2] = r0.z; ar[3] = r0.w;               \
        ar[4] = r1.x; ar[5] = r1.y; ar[6] = r1.z; ar[7] = r1.w;               \
    }

// T3 round-trip: CNOT perm folded (XOR scatter, b128 gather), fenced
#define XPOSE3(ar, ll)                                                        \
    {                                                                         \
        LDS_FENCE();                                                          \
        _Pragma("unroll")                                                     \
        for (int k = 0; k < 8; ++k)                                           \
            S[t3b[ll] ^ ((ll) ? S3_1.koff[k] : S3_0.koff[k])] = ar[k];        \
        LDS_FENCE();                                                          \
        const uint4 r0 = S4[(rb3[ll] >> 2)];                                  \
        const uint4 r1 = S4[(rb3[ll] >> 2) + 1];                              \
        ar[0] = r0.x; ar[1] = r0.y; ar[2] = r0.z; ar[3] = r0.w;               \
        ar[4] = r1.x; ar[5] = r1.y; ar[6] = r1.z; ar[7] = r1.w;               \
    }

// packed-fp16 boundary cmul from prefetched regs: a' = a * d, d = half2{dx,dy}
// (d pre-scaled by the layer's cosine product at qtab time)
#define CMUL_D(ar, dv)                                                        \
    {                                                                         \
        _Pragma("unroll")                                                     \
        for (int k = 0; k < 8; ++k) {                                         \
            const unsigned d = dv[k];                                         \
            unsigned t;                                                       \
            asm("v_pk_mul_f16 %0, %1, %2 op_sel:[1,1] op_sel_hi:[0,1] "       \
                "neg_lo:[0,1]"                                                \
                : "=v"(t) : "v"(ar[k]), "v"(d));                              \
            asm("v_pk_fma_f16 %0, %1, %2, %3 op_sel:[0,0,0] op_sel_hi:[1,0,1]"\
                : "=v"(ar[k]) : "v"(ar[k]), "v"(d), "v"(t));                  \
        }                                                                     \
    }

// init one element's state registers from x row `row` (v13 verbatim)
#define INIT_STATE(ar, row)                                                   \
    {                                                                         \
        float cx[9], sx[9];                                                   \
        _Pragma("unroll")                                                     \
        for (int w = 0; w < 9; ++w) {                                         \
            const float rev = x[(row) * 9 + w] * (0.5f * INV2PI);             \
            sx[w] = __builtin_amdgcn_sinf(rev);                               \
            cx[w] = __builtin_amdgcn_cosf(rev);                               \
        }                                                                     \
        float P = 1.0f;                                                       \
        _Pragma("unroll")                                                     \
        for (int w = 0; w < 6; ++w)                                           \
            P *= ((lane >> (5 - w)) & 1) ? sx[w] : cx[w];                     \
        float mk[8];                                                          \
        {                                                                     \
            const float m0 = P * cx[6],  m1 = P * sx[6];                      \
            const float m00 = m0 * cx[7], m01 = m0 * sx[7];                   \
            const float m10 = m1 * cx[7], m11 = m1 * sx[7];                   \
            mk[0] = m00 * cx[8]; mk[1] = m00 * sx[8];                         \
            mk[2] = m01 * cx[8]; mk[3] = m01 * sx[8];                         \
            mk[4] = m10 * cx[8]; mk[5] = m10 * sx[8];                         \
            mk[6] = m11 * cx[8]; mk[7] = m11 * sx[8];                         \
        }                                                                     \
        _Pragma("unroll")                                                     \
        for (int j2 = 0; j2 < 4; ++j2) {                                      \
            const float4 ph = PH4[(lane << 2) + j2];                          \
            ar[2 * j2]     = pack_rn(ph.x * mk[2 * j2],     ph.y * mk[2 * j2]);\
            ar[2 * j2 + 1] = pack_rn(ph.z * mk[2 * j2 + 1], ph.w * mk[2 * j2 + 1]);\
        }                                                                     \
    }

// epilogue: dot2 accumulation for one element into R0..R3
#define DOT2_ACC(ar, R0, R1, R2, R3)                                          \
    {                                                                         \
        _Pragma("unroll")                                                     \
        for (int k = 0; k < 8; ++k) {                                         \
            v2h h, hn;                                                        \
            { unsigned u = ar[k];               h  = *(const v2h*)&u; }       \
            { unsigned un = ar[k] ^ 0x80008000u; hn = *(const v2h*)&un; }     \
            R0 = __builtin_amdgcn_fdot2(h, h, R0, false);                     \
            R1 = __builtin_amdgcn_fdot2(h, (k & 4) ? hn : h, R1, false);      \
            R2 = __builtin_amdgcn_fdot2(h, (k & 2) ? hn : h, R2, false);      \
            R3 = __builtin_amdgcn_fdot2(h, (k & 1) ? hn : h, R3, false);      \
        }                                                                     \
    }

__global__ __launch_bounds__(256, 4) void qsim_kernel(
        const float* __restrict__ x,       // (batch, 9)
        const float* __restrict__ tab,     // ws tables
        float* __restrict__ out,           // (batch, 9)
        int batch) {
    __shared__ uint4 st4[4][128];          // per-wave staging (8 KiB total)

    const int tid  = threadIdx.x;
    const int wv   = tid >> 6;
    const int lane = tid & 63;
    const int b0   = (blockIdx.x * 4 + wv) * 4;     // FOUR elements per wave
    if (b0 >= batch) return;
    const int bu   = __builtin_amdgcn_readfirstlane(b0);  // wave-uniform
    const int buB  = (bu + 1 < batch) ? (bu + 1) : bu;
    const int buC  = (bu + 2 < batch) ? (bu + 2) : bu;
    const int buD  = (bu + 3 < batch) ? (bu + 3) : bu;

    unsigned* S = (unsigned*)st4[wv];      // may-alias with S4 (deliberate)
    const uint4* S4 = st4[wv];
    const unsigned* __restrict__ tu = (const unsigned*)tab;
    const unsigned* __restrict__ D0 = tu + 64;
    const unsigned* __restrict__ D1 = tu + 576;
    const float4*  __restrict__ PH4 = (const float4*)(tab + 1088);

    // ---- hoisted shared loads: 27 tan coeffs + final scale + D tables ----
    unsigned g[27];
    #pragma unroll
    for (int q = 0; q < 27; ++q) g[q] = tu[q];
    const float fscale = tab[27];          // (prod cos, layer 2)^2
    unsigned d0v[8], d1v[8];
    #pragma unroll
    for (int k = 0; k < 8; ++k) d0v[k] = D0[(k << 6) | lane];
    #pragma unroll
    for (int k = 0; k < 8; ++k) d1v[k] = D1[(k << 6) | lane];

    // ---- init all four elements ----
    unsigned aA[8], aB[8], aC[8], aD[8];
    INIT_STATE(aA, bu)
    INIT_STATE(aB, buB)
    INIT_STATE(aC, buC)
    INIT_STATE(aD, buD)

    // ---- per-transition address bases (v13 verbatim) ----
    const int wb1 = (lane & 31) | ((lane & 32) << 3);
    const int rb1 = ((lane & 7) << 5) | (lane & 0x18) | ((lane & 32) << 3);
    const int wb2 = ((lane >> 3) & 7) | ((lane & 3) << 3) | ((lane & 4) << 6);
    const int rb2 = ((lane & 3) << 3) | ((lane & 4) << 6) | ((lane & 0x38) << 2);
    int t3b[2], rb3[2];
    #pragma unroll
    for (int l = 0; l < 2; ++l) {
        int tb = 0, rb = 0;
        #pragma unroll
        for (int bb = 0; bb < 6; ++bb) {
            const int on = (lane >> bb) & 1;
            tb ^= on ? (l ? S3_1.wbasis[bb] : S3_0.wbasis[bb]) : 0;
            rb ^= on ? (1 << (l ? S3_1.rimg[bb] : S3_0.rimg[bb])) : 0;
        }
        t3b[l] = tb; rb3[l] = rb;
    }

    // ---- 3 layers, four elements phase-skewed; fenced LDS round-trips ----
    #pragma unroll
    for (int l = 0; l < 3; ++l) {
        APPLY_GATE(aA, g[l * 9 + 6], 4);   // layout A: q6,q7,q8
        APPLY_GATE(aA, g[l * 9 + 7], 2);
        APPLY_GATE(aA, g[l * 9 + 8], 1);
        XPOSE(aA, wb1, rb1);
        APPLY_GATE(aB, g[l * 9 + 6], 4);
        APPLY_GATE(aB, g[l * 9 + 7], 2);
        APPLY_GATE(aB, g[l * 9 + 8], 1);
        XPOSE(aB, wb1, rb1);
        APPLY_GATE(aC, g[l * 9 + 6], 4);
        APPLY_GATE(aC, g[l * 9 + 7], 2);
        APPLY_GATE(aC, g[l * 9 + 8], 1);
        XPOSE(aC, wb1, rb1);
        APPLY_GATE(aD, g[l * 9 + 6], 4);
        APPLY_GATE(aD, g[l * 9 + 7], 2);
        APPLY_GATE(aD, g[l * 9 + 8], 1);
        XPOSE(aD, wb1, rb1);

        APPLY_GATE(aA, g[l * 9 + 3], 4);   // layout B: q3,q4,q5
        APPLY_GATE(aA, g[l * 9 + 4], 2);
        APPLY_GATE(aA, g[l * 9 + 5], 1);
        XPOSE(aA, wb2, rb2);
        APPLY_GATE(aB, g[l * 9 + 3], 4);
        APPLY_GATE(aB, g[l * 9 + 4], 2);
        APPLY_GATE(aB, g[l * 9 + 5], 1);
        XPOSE(aB, wb2, rb2);
        APPLY_GATE(aC, g[l * 9 + 3], 4);
        APPLY_GATE(aC, g[l * 9 + 4], 2);
        APPLY_GATE(aC, g[l * 9 + 5], 1);
        XPOSE(aC, wb2, rb2);
        APPLY_GATE(aD, g[l * 9 + 3], 4);
        APPLY_GATE(aD, g[l * 9 + 4], 2);
        APPLY_GATE(aD, g[l * 9 + 5], 1);
        XPOSE(aD, wb2, rb2);

        APPLY_GATE(aA, g[l * 9 + 0], 4);   // layout C: q0,q1,q2
        APPLY_GATE(aA, g[l * 9 + 1], 2);
        APPLY_GATE(aA, g[l * 9 + 2], 1);
        if (l < 2) {
            if (l == 0) { CMUL_D(aA, d0v); } else { CMUL_D(aA, d1v); }
            XPOSE3(aA, l);
        }
        APPLY_GATE(aB, g[l * 9 + 0], 4);
        APPLY_GATE(aB, g[l * 9 + 1], 2);
        APPLY_GATE(aB, g[l * 9 + 2], 1);
        if (l < 2) {
            if (l == 0) { CMUL_D(aB, d0v); } else { CMUL_D(aB, d1v); }
            XPOSE3(aB, l);
        }
        APPLY_GATE(aC, g[l * 9 + 0], 4);
        APPLY_GATE(aC, g[l * 9 + 1], 2);
        APPLY_GATE(aC, g[l * 9 + 2], 1);
        if (l < 2) {
            if (l == 0) { CMUL_D(aC, d0v); } else { CMUL_D(aC, d1v); }
            XPOSE3(aC, l);
        }
        APPLY_GATE(aD, g[l * 9 + 0], 4);
        APPLY_GATE(aD, g[l * 9 + 1], 2);
        APPLY_GATE(aD, g[l * 9 + 2], 1);
        if (l < 2) {
            if (l == 0) { CMUL_D(aD, d0v); } else { CMUL_D(aD, d1v); }
            XPOSE3(aD, l);
        }
    }

    // ---- epilogue: dot2 accumulation + interleaved quad FWHT ----
    float A0 = 0.f, A1 = 0.f, A2 = 0.f, A3 = 0.f;
    float B0 = 0.f, B1 = 0.f, B2 = 0.f, B3 = 0.f;
    float C0 = 0.f, C1 = 0.f, C2 = 0.f, C3 = 0.f;
    float E0 = 0.f, E1 = 0.f, E2 = 0.f, E3 = 0.f;   // element D accumulators
    DOT2_ACC(aA, A0, A1, A2, A3)
    DOT2_ACC(aB, B0, B1, B2, B3)
    DOT2_ACC(aC, C0, C1, C2, C3)
    DOT2_ACC(aD, E0, E1, E2, E3)

    v2f FA01 = (v2f){A0, A1}, FA23 = (v2f){A2, A3};
    v2f FB01 = (v2f){B0, B1}, FB23 = (v2f){B2, B3};
    v2f FC01 = (v2f){C0, C1}, FC23 = (v2f){C2, C3};
    v2f FD01 = (v2f){E0, E1}, FD23 = (v2f){E2, E3};

    #pragma unroll
    for (int d = 1; d < 64; d <<= 1) {
        const float sg1 = (lane & d) ? -1.0f : 1.0f;
        const v2f sgn = (v2f){sg1, sg1};
        v2f p;
        p.x = __shfl_xor(FA01.x, d, 64);  p.y = __shfl_xor(FA01.y, d, 64);
        FA01 = FA01 * sgn + p;
        p.x = __shfl_xor(FA23.x, d, 64);  p.y = __shfl_xor(FA23.y, d, 64);
        FA23 = FA23 * sgn + p;
        p.x = __shfl_xor(FB01.x, d, 64);  p.y = __shfl_xor(FB01.y, d, 64);
        FB01 = FB01 * sgn + p;
        p.x = __shfl_xor(FB23.x, d, 64);  p.y = __shfl_xor(FB23.y, d, 64);
        FB23 = FB23 * sgn + p;
        p.x = __shfl_xor(FC01.x, d, 64);  p.y = __shfl_xor(FC01.y, d, 64);
        FC01 = FC01 * sgn + p;
        p.x = __shfl_xor(FC23.x, d, 64);  p.y = __shfl_xor(FC23.y, d, 64);
        FC23 = FC23 * sgn + p;
        p.x = __shfl_xor(FD01.x, d, 64);  p.y = __shfl_xor(FD01.y, d, 64);
        FD01 = FD01 * sgn + p;
        p.x = __shfl_xor(FD23.x, d, 64);  p.y = __shfl_xor(FD23.y, d, 64);
        FD23 = FD23 * sgn + p;
    }

    float* Sf = (float*)S;
    const int idx = (lane == 0) ? 72  : (lane == 1) ? 36  : (lane == 2) ? 18
                  : (lane == 3) ? 65  : (lane == 4) ? 160 : (lane == 5) ? 145
                  : (lane == 6) ? 73  : (lane == 7) ? 164 : 147;

    // pass 1: elements A,B
    LDS_FENCE();
    Sf[2 * lane]           = FA01.x;
    Sf[2 * lane + 1]       = FA01.y;
    Sf[128 + 2 * lane]     = FA23.x;
    Sf[128 + 2 * lane + 1] = FA23.y;
    Sf[256 + 2 * lane]     = FB01.x;
    Sf[256 + 2 * lane + 1] = FB01.y;
    Sf[384 + 2 * lane]     = FB23.x;
    Sf[384 + 2 * lane + 1] = FB23.y;
    LDS_FENCE();
    if (lane < 9) {
        out[bu * 9 + lane] = Sf[idx] * fscale;
        if (bu + 1 < batch) out[(bu + 1) * 9 + lane] = Sf[256 + idx] * fscale;
    }
    // pass 2: elements C,D reuse the buffer (fenced; per-wave DS in-order)
    LDS_FENCE();
    Sf[2 * lane]           = FC01.x;
    Sf[2 * lane + 1]       = FC01.y;
    Sf[128 + 2 * lane]     = FC23.x;
    Sf[128 + 2 * lane + 1] = FC23.y;
    Sf[256 + 2 * lane]     = FD01.x;
    Sf[256 + 2 * lane + 1] = FD01.y;
    Sf[384 + 2 * lane]     = FD23.x;
    Sf[384 + 2 * lane + 1] = FD23.y;
    LDS_FENCE();
    if (lane < 9) {
        if (bu + 2 < batch) out[(bu + 2) * 9 + lane] = Sf[idx] * fscale;
        if (bu + 3 < batch) out[(bu + 3) * 9 + lane] = Sf[256 + idx] * fscale;
    }
}

extern "C" void kernel_launch(void* const* d_in, const int* in_sizes, int n_in,
                              void* d_out, int out_size, void* d_ws, size_t ws_size,
                              hipStream_t stream) {
    const float* x  = (const float*)d_in[0];   // (32768, 9) fp32
    const float* wt = (const float*)d_in[1];   // (3, 9, 3) fp32
    float* out = (float*)d_out;                // (32768, 9) fp32
    const int batch = in_sizes[0] / 9;
    float* ws = (float*)d_ws;                  // 2112 floats = 8.4 KB used

    hipLaunchKernelGGL(qtab_kernel, dim3(1), dim3(512), 0, stream, wt, ws);
    hipLaunchKernelGGL(qsim_kernel, dim3((batch + 15) / 16), dim3(256), 0, stream,
                       x, ws, out, batch);
}

// Round 18
// 87.060 us; speedup vs baseline: 1.0255x; 1.0255x over previous
//
#include <hip/hip_runtime.h>
#include <hip/hip_fp16.h>

// ---------------------------------------------------------------------------
// 9-qubit batched state-vector simulator, v20 (FINAL — revert from v21).
// Session evidence chain:
//  - v13/v19: 2-elem phase-skew + fences + hoisting -> 47.7µs qsim.
//  - v20: tan-form gates (T=tan(theta/2), 2 FMA/pair; cosines folded into
//    D-tables at qtab time + one f32 output scale) -> qsim ~40µs,
//    headline 88.8µs. Best measured.
//  - v21 (4-elem + tan-form): FLAT (89.3) -> ILP lever dead at new balance.
// Structural floor: ~72 ds_write_b32 + ~17 ds_read_b128 per element
// ≈ 1240 DS-pipe cy/wave × 64 waves/CU ≈ 38µs — matches measured qsim ~40µs.
// qsim is LDS-instruction-throughput-bound in this 64-lane decomposition;
// remaining headline is harness memsets (40µs @ 83% HBM) + fixed overhead.
// ---------------------------------------------------------------------------

typedef float v2f __attribute__((ext_vector_type(2)));
typedef _Float16 v2h __attribute__((ext_vector_type(2)));

#define LDS_FENCE() asm volatile("" ::: "memory")

constexpr int pf(int l, int i) {        // forward CNOT-ring basis map, layer l
    const int r = l + 1; int j = i;
    for (int c = 0; c < 9; ++c) {
        const int bit = (j >> (8 - c)) & 1;
        const int t = (c + r) % 9;
        j ^= bit << (8 - t);
    }
    return j;
}

struct PMask { int m[2][9]; };
constexpr PMask make_pmask() {
    PMask pm{};
    for (int bd = 0; bd < 2; ++bd)
        for (int q = 0; q < 9; ++q) {
            const int img = pf(bd, 1 << q);
            for (int p = 0; p < 9; ++p)
                if ((img >> p) & 1) pm.m[bd][p] |= 1 << q;
        }
    return pm;
}
constexpr PMask PM = make_pmask();

// ---- sigma3 per boundary: img[b] = dest bit of source bit b; bits 0..2 id ----
struct Sig3 {
    int wbasis[6];   // sigma3(pf(l, 1<<b))        b = lane bit (C layout)
    int koff[8];     // sigma3(pf(l, k<<6))        k = reg index (C layout)
    int rimg[6];     // dest bit of source bit 3+b (for A-read base)
};
constexpr Sig3 make_sig3(int l) {
    Sig3 out{};
    for (int limit = 2; limit <= 64; limit *= 2) {
        for (int idx = 0; idx < 720; ++idx) {
            int pool[6] = {3, 4, 5, 6, 7, 8};
            int perm[6] = {};
            int f = idx;
            const int fact[6] = {120, 24, 6, 2, 1, 1};
            int n = 6;
            for (int pos = 0; pos < 6; ++pos) {
                const int sel = f / fact[pos]; f %= fact[pos];
                perm[pos] = pool[sel];
                for (int m2 = sel; m2 + 1 < n; ++m2) pool[m2] = pool[m2 + 1];
                --n;
            }
            int img[9] = {0, 1, 2, perm[0], perm[1], perm[2],
                          perm[3], perm[4], perm[5]};
            int cnt[32] = {};
            bool ok = true;
            for (int L = 0; L < 64 && ok; ++L) {
                const int j = pf(l, L);
                int addr = 0;
                for (int bb = 0; bb < 9; ++bb)
                    if ((j >> bb) & 1) addr ^= 1 << img[bb];
                if (++cnt[addr & 31] > limit) ok = false;
            }
            if (ok) {
                for (int b2 = 0; b2 < 6; ++b2) {
                    const int j = pf(l, 1 << b2); int v = 0;
                    for (int bb = 0; bb < 9; ++bb)
                        if ((j >> bb) & 1) v ^= 1 << img[bb];
                    out.wbasis[b2] = v;
                }
                for (int k = 0; k < 8; ++k) {
                    const int j = pf(l, k << 6); int v = 0;
                    for (int bb = 0; bb < 9; ++bb)
                        if ((j >> bb) & 1) v ^= 1 << img[bb];
                    out.koff[k] = v;
                }
                for (int b2 = 0; b2 < 6; ++b2) out.rimg[b2] = img[3 + b2];
                return out;
            }
        }
    }
    return out;
}
constexpr Sig3 S3_0 = make_sig3(0);
constexpr Sig3 S3_1 = make_sig3(1);

#define PI_F    3.14159265358979323846f
#define INV2PI  0.15915494309189535f

static __device__ inline unsigned pack_rn(float x, float y) {
    const __half2 h = __floats2half2_rn(x, y);
    return *(const unsigned*)&h;
}

// ws layout (u32/float units):
//   [0..27)       gates: 27 u32 = half2{T,T}, T = tan(theta/2)
//   [27]          f32 final scale = (prod_w cos(theta_l2_w/2))^2
//   [64..576)     D0h: 512 u32 = half2{dx,dy} * prodc(L0)  boundary 1->2
//   [576..1088)   D1h: 512 u32 = half2 * prodc(L1)         boundary 2->3
//   [1088..2112)  PH : 512 v2f (fp32) init-state phase
__global__ __launch_bounds__(512) void qtab_kernel(
        const float* __restrict__ wt, float* __restrict__ ws) {
    const int j = threadIdx.x;             // 0..511
    unsigned* wu = (unsigned*)ws;
    if (j < 27) {
        float s, c; __sincosf(0.5f * wt[j * 3 + 1], &s, &c);
        const float t = s / c;
        wu[j] = pack_rn(t, t);
    }
    // per-layer cosine products (wave-uniform; cheap, computed by all)
    float C[3];
    #pragma unroll
    for (int l = 0; l < 3; ++l) {
        float p = 1.0f;
        #pragma unroll
        for (int w = 0; w < 9; ++w) {
            float s, c; __sincosf(0.5f * wt[(l * 9 + w) * 3 + 1], &s, &c);
            p *= c;
        }
        C[l] = p;
    }
    if (j == 0) ws[27] = C[2] * C[2];
    #pragma unroll
    for (int bd = 0; bd < 2; ++bd) {
        float alpha = 0.0f;
        #pragma unroll
        for (int p = 0; p < 9; ++p) {
            const int w = 8 - p;
            const float om = wt[(bd * 9 + w) * 3 + 2];        // omega, layer bd
            const float ph = wt[((bd + 1) * 9 + w) * 3 + 0];  // phi, layer bd+1
            alpha += ((j >> p) & 1) ? 0.5f * om : -0.5f * om;
            alpha += (__popc(j & PM.m[bd][p]) & 1) ? 0.5f * ph : -0.5f * ph;
        }
        float sn, cs; __sincosf(alpha, &sn, &cs);
        wu[64 + bd * 512 + j] = pack_rn(cs * C[bd], sn * C[bd]);
    }
    {
        float a = 0.0f;
        #pragma unroll
        for (int p = 0; p < 9; ++p) {
            const int w = 8 - p;
            const float phi = wt[w * 3 + 0];
            a += ((j >> p) & 1) ? (0.5f * phi - 0.5f * PI_F) : (-0.5f * phi);
        }
        float sn, cs; __sincosf(a, &sn, &cs);
        ((v2f*)(ws + 1088))[j] = (v2f){cs, sn};
    }
}

// tan-form packed-fp16 real-Y gate, in-place, T from ONE SGPR = half2{t,t}:
//   a0' = a0 - T*a1 ; a1' = a1 + T*a0   (uniform cos factor deferred)
#define APPLY_GATE(ar, T, KB)                                                 \
    {                                                                         \
        _Pragma("unroll")                                                     \
        for (int k0 = 0; k0 < 8; ++k0) if (!(k0 & (KB))) {                    \
            const int k1 = k0 | (KB);                                         \
            unsigned t;                                                       \
            asm("v_pk_fma_f16 %0, %1, %2, %3 neg_lo:[1,0,0] neg_hi:[1,0,0]"   \
                : "=v"(t) : "s"(T), "v"(ar[k1]), "v"(ar[k0]));                \
            asm("v_pk_fma_f16 %0, %1, %2, %0"                                 \
                : "+v"(ar[k1]) : "s"(T), "v"(ar[k0]));                        \
            ar[k0] = t;                                                       \
        }                                                                     \
    }

// LDS round-trip transpose with compiler fences (cross-lane handoff is
// invisible to per-thread alias analysis — v16/v17 lesson)
#define XPOSE(ar, wb, rb)                                                     \
    {                                                                         \
        LDS_FENCE();                                                          \
        _Pragma("unroll")                                                     \
        for (int k = 0; k < 8; ++k) S[(wb) + (k << 5)] = ar[k];               \
        LDS_FENCE();                                                          \
        const uint4 r0 = S4[((rb) >> 2)];                                     \
        const uint4 r1 = S4[((rb) >> 2) + 1];                                 \
        ar[0] = r0.x; ar[1] = r0.y; ar[2] = r0.z; ar[3] = r0.w;               \
        ar[4] = r1.x; ar[5] = r1.y; ar[6] = r1.z; ar[7] = r1.w;               \
    }

// T3 round-trip: CNOT perm folded (XOR scatter, b128 gather), fenced
#define XPOSE3(ar, ll)                                                        \
    {                                                                         \
        LDS_FENCE();                                                          \
        _Pragma("unroll")                                                     \
        for (int k = 0; k < 8; ++k)                                           \
            S[t3b[ll] ^ ((ll) ? S3_1.koff[k] : S3_0.koff[k])] = ar[k];        \
        LDS_FENCE();                                                          \
        const uint4 r0 = S4[(rb3[ll] >> 2)];                                  \
        const uint4 r1 = S4[(rb3[ll] >> 2) + 1];                              \
        ar[0] = r0.x; ar[1] = r0.y; ar[2] = r0.z; ar[3] = r0.w;               \
        ar[4] = r1.x; ar[5] = r1.y; ar[6] = r1.z; ar[7] = r1.w;               \
    }

// packed-fp16 boundary cmul from prefetched regs: a' = a * d, d = half2{dx,dy}
// (d pre-scaled by the layer's cosine product at qtab time)
#define CMUL_D(ar, dv)                                                        \
    {                                                                         \
        _Pragma("unroll")                                                     \
        for (int k = 0; k < 8; ++k) {                                         \
            const unsigned d = dv[k];                                         \
            unsigned t;                                                       \
            asm("v_pk_mul_f16 %0, %1, %2 op_sel:[1,1] op_sel_hi:[0,1] "       \
                "neg_lo:[0,1]"                                                \
                : "=v"(t) : "v"(ar[k]), "v"(d));                              \
            asm("v_pk_fma_f16 %0, %1, %2, %3 op_sel:[0,0,0] op_sel_hi:[1,0,1]"\
                : "=v"(ar[k]) : "v"(ar[k]), "v"(d), "v"(t));                  \
        }                                                                     \
    }

// init one element's state registers from x row `row` (v13 verbatim)
#define INIT_STATE(ar, row)                                                   \
    {                                                                         \
        float cx[9], sx[9];                                                   \
        _Pragma("unroll")                                                     \
        for (int w = 0; w < 9; ++w) {                                         \
            const float rev = x[(row) * 9 + w] * (0.5f * INV2PI);             \
            sx[w] = __builtin_amdgcn_sinf(rev);                               \
            cx[w] = __builtin_amdgcn_cosf(rev);                               \
        }                                                                     \
        float P = 1.0f;                                                       \
        _Pragma("unroll")                                                     \
        for (int w = 0; w < 6; ++w)                                           \
            P *= ((lane >> (5 - w)) & 1) ? sx[w] : cx[w];                     \
        float mk[8];                                                          \
        {                                                                     \
            const float m0 = P * cx[6],  m1 = P * sx[6];                      \
            const float m00 = m0 * cx[7], m01 = m0 * sx[7];                   \
            const float m10 = m1 * cx[7], m11 = m1 * sx[7];                   \
            mk[0] = m00 * cx[8]; mk[1] = m00 * sx[8];                         \
            mk[2] = m01 * cx[8]; mk[3] = m01 * sx[8];                         \
            mk[4] = m10 * cx[8]; mk[5] = m10 * sx[8];                         \
            mk[6] = m11 * cx[8]; mk[7] = m11 * sx[8];                         \
        }                                                                     \
        _Pragma("unroll")                                                     \
        for (int j2 = 0; j2 < 4; ++j2) {                                      \
            const float4 ph = PH4[(lane << 2) + j2];                          \
            ar[2 * j2]     = pack_rn(ph.x * mk[2 * j2],     ph.y * mk[2 * j2]);\
            ar[2 * j2 + 1] = pack_rn(ph.z * mk[2 * j2 + 1], ph.w * mk[2 * j2 + 1]);\
        }                                                                     \
    }

__global__ __launch_bounds__(256, 4) void qsim_kernel(
        const float* __restrict__ x,       // (batch, 9)
        const float* __restrict__ tab,     // ws tables
        float* __restrict__ out,           // (batch, 9)
        int batch) {
    __shared__ uint4 st4[4][128];          // per-wave staging (8 KiB total)

    const int tid  = threadIdx.x;
    const int wv   = tid >> 6;
    const int lane = tid & 63;
    const int b0   = (blockIdx.x * 4 + wv) * 2;     // two elements per wave
    if (b0 >= batch) return;
    const int bu   = __builtin_amdgcn_readfirstlane(b0);  // wave-uniform
    const int buB  = (bu + 1 < batch) ? (bu + 1) : bu;    // clamped B row

    unsigned* S = (unsigned*)st4[wv];      // may-alias with S4 (deliberate)
    const uint4* S4 = st4[wv];
    const unsigned* __restrict__ tu = (const unsigned*)tab;
    const unsigned* __restrict__ D0 = tu + 64;
    const unsigned* __restrict__ D1 = tu + 576;
    const float4*  __restrict__ PH4 = (const float4*)(tab + 1088);

    // ---- hoisted shared loads: 27 tan coeffs + final scale + D tables ----
    unsigned g[27];
    #pragma unroll
    for (int q = 0; q < 27; ++q) g[q] = tu[q];
    const float fscale = tab[27];          // (prod cos, layer 2)^2
    unsigned d0v[8], d1v[8];
    #pragma unroll
    for (int k = 0; k < 8; ++k) d0v[k] = D0[(k << 6) | lane];
    #pragma unroll
    for (int k = 0; k < 8; ++k) d1v[k] = D1[(k << 6) | lane];

    // ---- init both elements ----
    unsigned aA[8], aB[8];
    INIT_STATE(aA, bu)
    INIT_STATE(aB, buB)

    // ---- per-transition address bases (v13 verbatim) ----
    const int wb1 = (lane & 31) | ((lane & 32) << 3);
    const int rb1 = ((lane & 7) << 5) | (lane & 0x18) | ((lane & 32) << 3);
    const int wb2 = ((lane >> 3) & 7) | ((lane & 3) << 3) | ((lane & 4) << 6);
    const int rb2 = ((lane & 3) << 3) | ((lane & 4) << 6) | ((lane & 0x38) << 2);
    int t3b[2], rb3[2];
    #pragma unroll
    for (int l = 0; l < 2; ++l) {
        int tb = 0, rb = 0;
        #pragma unroll
        for (int bb = 0; bb < 6; ++bb) {
            const int on = (lane >> bb) & 1;
            tb ^= on ? (l ? S3_1.wbasis[bb] : S3_0.wbasis[bb]) : 0;
            rb ^= on ? (1 << (l ? S3_1.rimg[bb] : S3_0.rimg[bb])) : 0;
        }
        t3b[l] = tb; rb3[l] = rb;
    }

    // ---- 3 layers, elements phase-skewed: A.gates|A.xpose|B.gates|B.xpose.
    #pragma unroll
    for (int l = 0; l < 3; ++l) {
        APPLY_GATE(aA, g[l * 9 + 6], 4);   // layout A: reg bits = q6,q7,q8
        APPLY_GATE(aA, g[l * 9 + 7], 2);
        APPLY_GATE(aA, g[l * 9 + 8], 1);
        XPOSE(aA, wb1, rb1);
        APPLY_GATE(aB, g[l * 9 + 6], 4);
        APPLY_GATE(aB, g[l * 9 + 7], 2);
        APPLY_GATE(aB, g[l * 9 + 8], 1);
        XPOSE(aB, wb1, rb1);

        APPLY_GATE(aA, g[l * 9 + 3], 4);   // layout B: reg bits = q3,q4,q5
        APPLY_GATE(aA, g[l * 9 + 4], 2);
        APPLY_GATE(aA, g[l * 9 + 5], 1);
        XPOSE(aA, wb2, rb2);
        APPLY_GATE(aB, g[l * 9 + 3], 4);
        APPLY_GATE(aB, g[l * 9 + 4], 2);
        APPLY_GATE(aB, g[l * 9 + 5], 1);
        XPOSE(aB, wb2, rb2);

        APPLY_GATE(aA, g[l * 9 + 0], 4);   // layout C: reg bits = q0,q1,q2
        APPLY_GATE(aA, g[l * 9 + 1], 2);
        APPLY_GATE(aA, g[l * 9 + 2], 1);
        if (l < 2) {
            if (l == 0) { CMUL_D(aA, d0v); } else { CMUL_D(aA, d1v); }
            XPOSE3(aA, l);
        }
        APPLY_GATE(aB, g[l * 9 + 0], 4);
        APPLY_GATE(aB, g[l * 9 + 1], 2);
        APPLY_GATE(aB, g[l * 9 + 2], 1);
        if (l < 2) {
            if (l == 0) { CMUL_D(aB, d0v); } else { CMUL_D(aB, d1v); }
            XPOSE3(aB, l);
        }
    }

    // ---- epilogue: dot2 accumulation + interleaved dual FWHT ----
    float A0 = 0.f, A1 = 0.f, A2 = 0.f, A3 = 0.f;
    float B0 = 0.f, B1 = 0.f, B2 = 0.f, B3 = 0.f;
    #pragma unroll
    for (int k = 0; k < 8; ++k) {
#if __has_builtin(__builtin_amdgcn_fdot2)
        v2h h, hn;
        { unsigned u = aA[k];               h = *(const v2h*)&u; }
        { unsigned un = aA[k] ^ 0x80008000u; hn = *(const v2h*)&un; }
        A0 = __builtin_amdgcn_fdot2(h, h, A0, false);
        A1 = __builtin_amdgcn_fdot2(h, (k & 4) ? hn : h, A1, false);
        A2 = __builtin_amdgcn_fdot2(h, (k & 2) ? hn : h, A2, false);
        A3 = __builtin_amdgcn_fdot2(h, (k & 1) ? hn : h, A3, false);
        { unsigned u = aB[k];               h = *(const v2h*)&u; }
        { unsigned un = aB[k] ^ 0x80008000u; hn = *(const v2h*)&un; }
        B0 = __builtin_amdgcn_fdot2(h, h, B0, false);
        B1 = __builtin_amdgcn_fdot2(h, (k & 4) ? hn : h, B1, false);
        B2 = __builtin_amdgcn_fdot2(h, (k & 2) ? hn : h, B2, false);
        B3 = __builtin_amdgcn_fdot2(h, (k & 1) ? hn : h, B3, false);
#else
        {
            const __half2 h = *(const __half2*)&aA[k];
            const float2 f = __half22float2(h);
            const float p = f.x * f.x + f.y * f.y;
            A0 += p;
            A1 += (k & 4) ? -p : p;
            A2 += (k & 2) ? -p : p;
            A3 += (k & 1) ? -p : p;
        }
        {
            const __half2 h = *(const __half2*)&aB[k];
            const float2 f = __half22float2(h);
            const float p = f.x * f.x + f.y * f.y;
            B0 += p;
            B1 += (k & 4) ? -p : p;
            B2 += (k & 2) ? -p : p;
            B3 += (k & 1) ? -p : p;
        }
#endif
    }
    v2f FA01 = (v2f){A0, A1};   // {F_S, F_U4}
    v2f FA23 = (v2f){A2, A3};   // {F_U2, F_U1}
    v2f FB01 = (v2f){B0, B1};
    v2f FB23 = (v2f){B2, B3};

    #pragma unroll
    for (int d = 1; d < 64; d <<= 1) {
        const float sg1 = (lane & d) ? -1.0f : 1.0f;
        const v2f sgn = (v2f){sg1, sg1};
        v2f pA01, pA23, pB01, pB23;
        pA01.x = __shfl_xor(FA01.x, d, 64);  pA01.y = __shfl_xor(FA01.y, d, 64);
        pA23.x = __shfl_xor(FA23.x, d, 64);  pA23.y = __shfl_xor(FA23.y, d, 64);
        pB01.x = __shfl_xor(FB01.x, d, 64);  pB01.y = __shfl_xor(FB01.y, d, 64);
        pB23.x = __shfl_xor(FB23.x, d, 64);  pB23.y = __shfl_xor(FB23.y, d, 64);
        FA01 = FA01 * sgn + pA01;
        FA23 = FA23 * sgn + pA23;
        FB01 = FB01 * sgn + pB01;
        FB23 = FB23 * sgn + pB23;
    }
    float* Sf = (float*)S;
    LDS_FENCE();
    Sf[2 * lane]           = FA01.x;
    Sf[2 * lane + 1]       = FA01.y;
    Sf[128 + 2 * lane]     = FA23.x;
    Sf[128 + 2 * lane + 1] = FA23.y;
    Sf[256 + 2 * lane]     = FB01.x;
    Sf[256 + 2 * lane + 1] = FB01.y;
    Sf[384 + 2 * lane]     = FB23.x;
    Sf[384 + 2 * lane + 1] = FB23.y;
    LDS_FENCE();
    if (lane < 9) {
        const int idx = (lane == 0) ? 72  : (lane == 1) ? 36  : (lane == 2) ? 18
                      : (lane == 3) ? 65  : (lane == 4) ? 160 : (lane == 5) ? 145
                      : (lane == 6) ? 73  : (lane == 7) ? 164 : 147;
        out[bu * 9 + lane] = Sf[idx] * fscale;
        if (bu + 1 < batch) out[(bu + 1) * 9 + lane] = Sf[256 + idx] * fscale;
    }
}

extern "C" void kernel_launch(void* const* d_in, const int* in_sizes, int n_in,
                              void* d_out, int out_size, void* d_ws, size_t ws_size,
                              hipStream_t stream) {
    const float* x  = (const float*)d_in[0];   // (32768, 9) fp32
    const float* wt = (const float*)d_in[1];   // (3, 9, 3) fp32
    float* out = (float*)d_out;                // (32768, 9) fp32
    const int batch = in_sizes[0] / 9;
    float* ws = (float*)d_ws;                  // 2112 floats = 8.4 KB used

    hipLaunchKernelGGL(qtab_kernel, dim3(1), dim3(512), 0, stream, wt, ws);
    hipLaunchKernelGGL(qsim_kernel, dim3((batch + 7) / 8), dim3(256), 0, stream,
                       x, ws, out, batch);
}